// Round 6
// baseline (1114.804 us; speedup 1.0000x reference)
//
#include <hip/hip_runtime.h>
#include <hip/hip_fp16.h>

typedef __attribute__((ext_vector_type(8))) short bf16x8;
typedef __attribute__((ext_vector_type(4))) float f32x4;

__device__ __forceinline__ f32x4 mfma16(bf16x8 a, bf16x8 b, f32x4 c) {
    return __builtin_amdgcn_mfma_f32_16x16x32_bf16(a, b, c, 0, 0, 0);
}

__device__ __forceinline__ unsigned short bf16_rte(float f) {
    unsigned int u = __float_as_uint(f);
    unsigned int r = (u + 0x7FFFu + ((u >> 16) & 1u)) >> 16;
    return (unsigned short)r;
}
__device__ __forceinline__ float bf16_f(unsigned short h) {
    return __uint_as_float(((unsigned int)h) << 16);
}

// ---------------- bucketed CSR build ----------------
// bucket b = dst >> 7 (128 nodes/bucket). Writes concentrate on ~NB open
// lines -> merge in L2 (vs round-5 scatter: 105 MB of line thrash).

__global__ void k_bcount(const int* __restrict__ dst, int* __restrict__ bcnt, int E) {
    int e = blockIdx.x * blockDim.x + threadIdx.x;
    if (e < E) atomicAdd(&bcnt[dst[e] >> 7], 1);
}

// single block, 1024 threads: exclusive scan of bcnt[nb] -> boff, bcur
__global__ void k_bscan(const int* __restrict__ bcnt, int* __restrict__ boff,
                        int* __restrict__ bcur, int nb) {
    __shared__ int sh[1024];
    int t = threadIdx.x;
    int v = (t < nb) ? bcnt[t] : 0;
    sh[t] = v;
    __syncthreads();
    for (int off = 1; off < 1024; off <<= 1) {
        int u = (t >= off) ? sh[t - off] : 0;
        __syncthreads();
        sh[t] += u;
        __syncthreads();
    }
    if (t < nb) {
        int ex = sh[t] - v;
        boff[t] = ex;
        bcur[t] = ex;
    }
}

__global__ void k_bscatter(const int* __restrict__ src, const int* __restrict__ dst,
                           int* __restrict__ bcur, int2* __restrict__ pairs, int E) {
    int e = blockIdx.x * blockDim.x + threadIdx.x;
    if (e < E) {
        int d = dst[e];
        int p = atomicAdd(&bcur[d >> 7], 1);
        pairs[p] = make_int2(d, src[e]);
    }
}

// one block per bucket: LDS count + LDS scan + LDS-cursor place.
// Emits csr, start, deg. Bucket region ~16 KB -> L1/L2-resident.
__global__ __launch_bounds__(256) void k_build(
    const int2* __restrict__ pairs, const int* __restrict__ boff,
    int* __restrict__ csr, int* __restrict__ start, int* __restrict__ deg,
    int n, int nb, int E) {
    __shared__ int scnt[128];
    __shared__ int soff[128];
    __shared__ int cur[128];
    int b = blockIdx.x;
    int t = threadIdx.x;
    int base = boff[b];
    int end = (b + 1 < nb) ? boff[b + 1] : E;
    if (t < 128) scnt[t] = 0;
    __syncthreads();
    for (int i = base + t; i < end; i += 256) {
        int2 e = pairs[i];
        atomicAdd(&scnt[e.x & 127], 1);
    }
    __syncthreads();
    // inclusive scan of scnt into soff (128 entries)
    if (t < 128) soff[t] = scnt[t];
    __syncthreads();
    for (int off = 1; off < 128; off <<= 1) {
        int val = 0;
        if (t < 128 && t >= off) val = soff[t - off];
        __syncthreads();
        if (t < 128) soff[t] += val;
        __syncthreads();
    }
    if (t < 128) {
        int c = scnt[t];
        int ex = soff[t] - c;
        int node = b * 128 + t;
        if (node < n) {
            start[node] = base + ex;
            deg[node] = c;
        }
        cur[t] = base + ex;
    }
    __syncthreads();
    for (int i = base + t; i < end; i += 256) {
        int2 e = pairs[i];
        int p = atomicAdd(&cur[e.x & 127], 1);
        csr[p] = e.y;
    }
}

// ---------------- MFMA dual GEMM (bf16x3 split = fp32-grade accuracy) --------
// ysel=0: dstH = X@WA (fp16);  ysel=1: dstF = X@WB + bias (fp32).

#define SR 40  // LDS row stride in ushorts

template <int FOUT>
__device__ __forceinline__ void gemm_body(
    const float* __restrict__ X, const float* __restrict__ WA,
    const float* __restrict__ WB, const float* __restrict__ bias,
    __half* __restrict__ dstH, float* __restrict__ dstF, int n) {
    constexpr int CT = FOUT / 32;
    __shared__ unsigned short aHi[128 * SR], aLo[128 * SR];
    __shared__ unsigned short wHi[FOUT * SR], wLo[FOUT * SR];

    int t = threadIdx.x;
    int wv = t >> 6, l = t & 63, q = l >> 4, nl = l & 15;
    int wn = (wv & 1) * 64, wc = (wv >> 1) * (FOUT / 2);
    int node0 = blockIdx.x * 128;
    int ysel = blockIdx.y;
    const float* W = ysel ? WB : WA;

    int sn = t >> 1, sh2 = t & 1;
    int gn = min(node0 + sn, n - 1);

    f32x4 acc[4][CT];
#pragma unroll
    for (int a = 0; a < 4; ++a)
#pragma unroll
        for (int b = 0; b < CT; ++b) acc[a][b] = (f32x4){0.f, 0.f, 0.f, 0.f};

    for (int c = 0; c < 4; ++c) {
        int k0 = c * 32;
        {
            const float4* ap = (const float4*)(X + (size_t)gn * 128 + k0);
#pragma unroll
            for (int i = 0; i < 4; ++i) {
                float4 v = ap[sh2 * 4 + i];
                int base = sn * SR + sh2 * 16 + i * 4;
                ushort4 hi, lo;
                hi.x = bf16_rte(v.x); lo.x = bf16_rte(v.x - bf16_f(hi.x));
                hi.y = bf16_rte(v.y); lo.y = bf16_rte(v.y - bf16_f(hi.y));
                hi.z = bf16_rte(v.z); lo.z = bf16_rte(v.z - bf16_f(hi.z));
                hi.w = bf16_rte(v.w); lo.w = bf16_rte(v.w - bf16_f(hi.w));
                *(ushort4*)&aHi[base] = hi;
                *(ushort4*)&aLo[base] = lo;
            }
        }
        {
#pragma unroll
            for (int rep = 0; rep < FOUT / 32; ++rep) {
                int idx = t + rep * 256;
                int fk = idx / (FOUT / 4);
                int fc = (idx % (FOUT / 4)) * 4;
                float4 v = *(const float4*)(W + (size_t)(k0 + fk) * FOUT + fc);
                const float* vp = &v.x;
#pragma unroll
                for (int s = 0; s < 4; ++s) {
                    unsigned short hi = bf16_rte(vp[s]);
                    wHi[(fc + s) * SR + fk] = hi;
                    wLo[(fc + s) * SR + fk] = bf16_rte(vp[s] - bf16_f(hi));
                }
            }
        }
        __syncthreads();

        bf16x8 ah[4], al[4], wh[CT], wl2[CT];
#pragma unroll
        for (int tt = 0; tt < 4; ++tt) {
            int off = (wn + tt * 16 + nl) * SR + q * 8;
            ah[tt] = *(const bf16x8*)&aHi[off];
            al[tt] = *(const bf16x8*)&aLo[off];
        }
#pragma unroll
        for (int uu = 0; uu < CT; ++uu) {
            int off = (wc + uu * 16 + nl) * SR + q * 8;
            wh[uu] = *(const bf16x8*)&wHi[off];
            wl2[uu] = *(const bf16x8*)&wLo[off];
        }
#pragma unroll
        for (int tt = 0; tt < 4; ++tt)
#pragma unroll
            for (int uu = 0; uu < CT; ++uu) {
                f32x4 a = acc[tt][uu];
                a = mfma16(al[tt], wh[uu], a);
                a = mfma16(ah[tt], wl2[uu], a);
                a = mfma16(ah[tt], wh[uu], a);
                acc[tt][uu] = a;
            }
        __syncthreads();
    }

#pragma unroll
    for (int uu = 0; uu < CT; ++uu) {
        int col = wc + uu * 16 + nl;
        if (ysel) {
            float bv = bias[col];
#pragma unroll
            for (int tt = 0; tt < 4; ++tt)
#pragma unroll
                for (int r = 0; r < 4; ++r) {
                    int node = node0 + wn + tt * 16 + q * 4 + r;
                    if (node < n) dstF[(size_t)node * FOUT + col] = acc[tt][uu][r] + bv;
                }
        } else {
#pragma unroll
            for (int tt = 0; tt < 4; ++tt)
#pragma unroll
                for (int r = 0; r < 4; ++r) {
                    int node = node0 + wn + tt * 16 + q * 4 + r;
                    if (node < n) dstH[(size_t)node * FOUT + col] = __float2half(acc[tt][uu][r]);
                }
        }
    }
}

__global__ __launch_bounds__(256, 2) void gemm1(
    const float* __restrict__ X, const float* __restrict__ WA,
    const float* __restrict__ WB, const float* __restrict__ bias,
    __half* __restrict__ dstH, float* __restrict__ dstF, int n) {
    gemm_body<128>(X, WA, WB, bias, dstH, dstF, n);
}

__global__ __launch_bounds__(256, 2) void gemm2(
    const float* __restrict__ X, const float* __restrict__ WA,
    const float* __restrict__ WB, const float* __restrict__ bias,
    __half* __restrict__ dstH, float* __restrict__ dstF, int n) {
    gemm_body<64>(X, WA, WB, bias, dstH, dstF, n);
}

// ---------------- fused aggregations (2 nodes/wave, wide loads) --------------

// h = relu(mean-gather(u fp16) + v). 2 nodes/wave: 32 lanes x 8 B per edge.
__global__ void agg1(const __half* __restrict__ u, const float* __restrict__ v,
                     const int* __restrict__ csr, const int* __restrict__ start,
                     const int* __restrict__ deg, float* __restrict__ h, int n) {
    int gid = blockIdx.x * blockDim.x + threadIdx.x;
    int wave = gid >> 6, lane = gid & 63;
    int half = lane >> 5, fl = lane & 31;
    int node = wave * 2 + half;
    if (node >= n) return;
    int s = start[node], d = deg[node];
    const float2* u2 = (const float2*)u;  // 4 halfs per float2
    float4 acc = {0.f, 0.f, 0.f, 0.f};
    int j = 0;
    for (; j + 2 <= d; j += 2) {
        int i0 = csr[s + j], i1 = csr[s + j + 1];
        float2 r0 = u2[(size_t)i0 * 32 + fl];
        float2 r1 = u2[(size_t)i1 * 32 + fl];
        float2 a0 = __half22float2(*(const __half2*)&r0.x);
        float2 b0 = __half22float2(*(const __half2*)&r0.y);
        float2 a1 = __half22float2(*(const __half2*)&r1.x);
        float2 b1 = __half22float2(*(const __half2*)&r1.y);
        acc.x += a0.x + a1.x;
        acc.y += a0.y + a1.y;
        acc.z += b0.x + b1.x;
        acc.w += b0.y + b1.y;
    }
    if (j < d) {
        float2 r0 = u2[(size_t)csr[s + j] * 32 + fl];
        float2 a0 = __half22float2(*(const __half2*)&r0.x);
        float2 b0 = __half22float2(*(const __half2*)&r0.y);
        acc.x += a0.x; acc.y += a0.y; acc.z += b0.x; acc.w += b0.y;
    }
    float inv = 1.0f / (float)max(d, 1);
    float4 vv = ((const float4*)v)[(size_t)node * 32 + fl];
    float4 r;
    r.x = fmaxf(acc.x * inv + vv.x, 0.f);
    r.y = fmaxf(acc.y * inv + vv.y, 0.f);
    r.z = fmaxf(acc.z * inv + vv.z, 0.f);
    r.w = fmaxf(acc.w * inv + vv.w, 0.f);
    ((float4*)h)[(size_t)node * 32 + fl] = r;
}

// out += mean-gather(p fp16). 2 nodes/wave: 32 lanes x 4 B per edge.
__global__ void agg2(const __half* __restrict__ p, const int* __restrict__ csr,
                     const int* __restrict__ start, const int* __restrict__ deg,
                     float* __restrict__ out, int n) {
    int gid = blockIdx.x * blockDim.x + threadIdx.x;
    int wave = gid >> 6, lane = gid & 63;
    int half = lane >> 5, fl = lane & 31;
    int node = wave * 2 + half;
    if (node >= n) return;
    int s = start[node], d = deg[node];
    const __half2* p2 = (const __half2*)p;
    float ax = 0.f, ay = 0.f, bx = 0.f, by = 0.f;
    int j = 0;
    for (; j + 2 <= d; j += 2) {
        int i0 = csr[s + j], i1 = csr[s + j + 1];
        float2 v0 = __half22float2(p2[(size_t)i0 * 32 + fl]);
        float2 v1 = __half22float2(p2[(size_t)i1 * 32 + fl]);
        ax += v0.x; ay += v0.y;
        bx += v1.x; by += v1.y;
    }
    if (j < d) {
        float2 v0 = __half22float2(p2[(size_t)csr[s + j] * 32 + fl]);
        ax += v0.x; ay += v0.y;
    }
    float inv = 1.0f / (float)max(d, 1);
    size_t o = (size_t)node * 32 + fl;
    float2 cu = ((float2*)out)[o];
    cu.x += (ax + bx) * inv;
    cu.y += (ay + by) * inv;
    ((float2*)out)[o] = cu;
}

// ---------------- launch ----------------

extern "C" void kernel_launch(void* const* d_in, const int* in_sizes, int n_in,
                              void* d_out, int out_size, void* d_ws, size_t ws_size,
                              hipStream_t stream) {
    const float* x   = (const float*)d_in[0];
    const int*   ei  = (const int*)d_in[1];
    const float* Wl1 = (const float*)d_in[2];
    const float* Wr1 = (const float*)d_in[3];
    const float* b1  = (const float*)d_in[4];
    const float* Wl2 = (const float*)d_in[5];
    const float* Wr2 = (const float*)d_in[6];
    const float* b2  = (const float*)d_in[7];
    float* out = (float*)d_out;

    int Nn = in_sizes[0] / 128;
    int E  = in_sizes[1] / 2;
    const int* src = ei;
    const int* dst = ei + E;
    int nb = (Nn + 127) / 128;  // buckets of 128 nodes; 782 <= 1024

    char* ws = (char*)d_ws;
    auto alloc = [&](size_t bytes) -> char* {
        char* pp = ws;
        ws += (bytes + 255) / 256 * 256;
        return pp;
    };
    int* bcnt   = (int*)alloc((size_t)nb * 4);
    int* boff   = (int*)alloc((size_t)nb * 4);
    int* bcur   = (int*)alloc((size_t)nb * 4);
    int* start  = (int*)alloc((size_t)Nn * 4);
    int* deg    = (int*)alloc((size_t)Nn * 4);
    int* csr    = (int*)alloc((size_t)E * 4);
    __half* u   = (__half*)alloc((size_t)Nn * 128 * 2);
    float* v    = (float*)alloc((size_t)Nn * 128 * 4);
    float* h    = (float*)alloc((size_t)Nn * 128 * 4);
    __half* p   = (__half*)alloc((size_t)Nn * 64 * 2);
    // pairs (12.8 MB) aliases v (51.2 MB): consumed by k_build before gemm1 writes v
    int2* pairs = (int2*)v;

    hipMemsetAsync(bcnt, 0, (size_t)nb * 4, stream);

    k_bcount<<<(E + 255) / 256, 256, 0, stream>>>(dst, bcnt, E);
    k_bscan<<<1, 1024, 0, stream>>>(bcnt, boff, bcur, nb);
    k_bscatter<<<(E + 255) / 256, 256, 0, stream>>>(src, dst, bcur, pairs, E);
    k_build<<<nb, 256, 0, stream>>>(pairs, boff, csr, start, deg, Nn, nb, E);

    dim3 gg((Nn + 127) / 128, 2);
    // layer 1 (linearity): u = x@Wl1 (fp16), v = x@Wr1 + b1; h = relu(agg(u) + v)
    gemm1<<<gg, 256, 0, stream>>>(x, Wl1, Wr1, b1, u, v, Nn);
    agg1<<<(Nn + 7) / 8, 256, 0, stream>>>(u, v, csr, start, deg, h, Nn);
    // layer 2 (linearity): p = h@Wl2 (fp16), out = h@Wr2 + b2; out += agg(p)
    gemm2<<<gg, 256, 0, stream>>>(h, Wl2, Wr2, b2, p, out, Nn);
    agg2<<<(Nn + 7) / 8, 256, 0, stream>>>(p, csr, start, deg, out, Nn);
}

// Round 7
// 419.822 us; speedup vs baseline: 2.6554x; 2.6554x over previous
//
#include <hip/hip_runtime.h>
#include <hip/hip_fp16.h>

typedef __attribute__((ext_vector_type(8))) short bf16x8;
typedef __attribute__((ext_vector_type(4))) float f32x4;

__device__ __forceinline__ f32x4 mfma16(bf16x8 a, bf16x8 b, f32x4 c) {
    return __builtin_amdgcn_mfma_f32_16x16x32_bf16(a, b, c, 0, 0, 0);
}

__device__ __forceinline__ unsigned short bf16_rte(float f) {
    unsigned int u = __float_as_uint(f);
    unsigned int r = (u + 0x7FFFu + ((u >> 16) & 1u)) >> 16;
    return (unsigned short)r;
}
__device__ __forceinline__ float bf16_f(unsigned short h) {
    return __uint_as_float(((unsigned int)h) << 16);
}

// ---------------- bucketed CSR build, two-level (contention-free) ------------
// bucket b = dst >> 7 (128 nodes/bucket, nb<=1024). Round-6 lesson: 1.6M global
// atomics on 782 addrs = ~185 ns/op serialized = 378 us. Fix: LDS histograms,
// then <=256 global atomics per address (parallel across addrs).

#define MAXNB 1024

__global__ __launch_bounds__(256) void k_bcount(
    const int* __restrict__ dst, int* __restrict__ bcnt, int E, int chunk, int nb) {
    __shared__ int h[MAXNB];
    int t = threadIdx.x;
    for (int i = t; i < nb; i += 256) h[i] = 0;
    __syncthreads();
    int base = blockIdx.x * chunk;
    int end = min(base + chunk, E);
    for (int i = base + t; i < end; i += 256) atomicAdd(&h[dst[i] >> 7], 1);
    __syncthreads();
    for (int i = t; i < nb; i += 256)
        if (h[i]) atomicAdd(&bcnt[i], h[i]);
}

// single block: exclusive scan of bcnt -> boff, bcur
__global__ void k_bscan(const int* __restrict__ bcnt, int* __restrict__ boff,
                        int* __restrict__ bcur, int nb) {
    __shared__ int sh[1024];
    int t = threadIdx.x;
    int v = (t < nb) ? bcnt[t] : 0;
    sh[t] = v;
    __syncthreads();
    for (int off = 1; off < 1024; off <<= 1) {
        int u = (t >= off) ? sh[t - off] : 0;
        __syncthreads();
        sh[t] += u;
        __syncthreads();
    }
    if (t < nb) {
        int ex = sh[t] - v;
        boff[t] = ex;
        bcur[t] = ex;
    }
}

// LDS histogram -> per-bucket range reservation -> scatter via LDS cursors.
__global__ __launch_bounds__(256) void k_bscatter(
    const int* __restrict__ src, const int* __restrict__ dst,
    int* __restrict__ bcur, int2* __restrict__ pairs, int E, int chunk, int nb) {
    __shared__ int h[MAXNB];
    __shared__ int curs[MAXNB];
    int t = threadIdx.x;
    for (int i = t; i < nb; i += 256) h[i] = 0;
    __syncthreads();
    int base = blockIdx.x * chunk;
    int end = min(base + chunk, E);
    for (int i = base + t; i < end; i += 256) atomicAdd(&h[dst[i] >> 7], 1);
    __syncthreads();
    for (int i = t; i < nb; i += 256)
        curs[i] = h[i] ? atomicAdd(&bcur[i], h[i]) : 0;
    __syncthreads();
    for (int i = base + t; i < end; i += 256) {
        int d = dst[i];
        int p = atomicAdd(&curs[d >> 7], 1);
        pairs[p] = make_int2(d, src[i]);
    }
}

// one block per bucket: LDS count + LDS scan + LDS-cursor place.
// Emits csr, start, deg. Bucket region ~16 KB -> L2-resident.
__global__ __launch_bounds__(256) void k_build(
    const int2* __restrict__ pairs, const int* __restrict__ boff,
    int* __restrict__ csr, int* __restrict__ start, int* __restrict__ deg,
    int n, int nb, int E) {
    __shared__ int scnt[128];
    __shared__ int soff[128];
    __shared__ int cur[128];
    int b = blockIdx.x;
    int t = threadIdx.x;
    int base = boff[b];
    int end = (b + 1 < nb) ? boff[b + 1] : E;
    if (t < 128) scnt[t] = 0;
    __syncthreads();
    for (int i = base + t; i < end; i += 256) {
        int2 e = pairs[i];
        atomicAdd(&scnt[e.x & 127], 1);
    }
    __syncthreads();
    if (t < 128) soff[t] = scnt[t];
    __syncthreads();
    for (int off = 1; off < 128; off <<= 1) {
        int val = 0;
        if (t < 128 && t >= off) val = soff[t - off];
        __syncthreads();
        if (t < 128) soff[t] += val;
        __syncthreads();
    }
    if (t < 128) {
        int c = scnt[t];
        int ex = soff[t] - c;
        int node = b * 128 + t;
        if (node < n) {
            start[node] = base + ex;
            deg[node] = c;
        }
        cur[t] = base + ex;
    }
    __syncthreads();
    for (int i = base + t; i < end; i += 256) {
        int2 e = pairs[i];
        int p = atomicAdd(&cur[e.x & 127], 1);
        csr[p] = e.y;
    }
}

// ---------------- MFMA dual GEMM (bf16x3 split = fp32-grade accuracy) --------
// ysel=0: dstH = X@WA (fp16);  ysel=1: dstF = X@WB + bias (fp32).

#define SR 40  // LDS row stride in ushorts

template <int FOUT>
__device__ __forceinline__ void gemm_body(
    const float* __restrict__ X, const float* __restrict__ WA,
    const float* __restrict__ WB, const float* __restrict__ bias,
    __half* __restrict__ dstH, float* __restrict__ dstF, int n) {
    constexpr int CT = FOUT / 32;
    __shared__ unsigned short aHi[128 * SR], aLo[128 * SR];
    __shared__ unsigned short wHi[FOUT * SR], wLo[FOUT * SR];

    int t = threadIdx.x;
    int wv = t >> 6, l = t & 63, q = l >> 4, nl = l & 15;
    int wn = (wv & 1) * 64, wc = (wv >> 1) * (FOUT / 2);
    int node0 = blockIdx.x * 128;
    int ysel = blockIdx.y;
    const float* W = ysel ? WB : WA;

    int sn = t >> 1, sh2 = t & 1;
    int gn = min(node0 + sn, n - 1);

    f32x4 acc[4][CT];
#pragma unroll
    for (int a = 0; a < 4; ++a)
#pragma unroll
        for (int b = 0; b < CT; ++b) acc[a][b] = (f32x4){0.f, 0.f, 0.f, 0.f};

    for (int c = 0; c < 4; ++c) {
        int k0 = c * 32;
        {
            const float4* ap = (const float4*)(X + (size_t)gn * 128 + k0);
#pragma unroll
            for (int i = 0; i < 4; ++i) {
                float4 v = ap[sh2 * 4 + i];
                int base = sn * SR + sh2 * 16 + i * 4;
                ushort4 hi, lo;
                hi.x = bf16_rte(v.x); lo.x = bf16_rte(v.x - bf16_f(hi.x));
                hi.y = bf16_rte(v.y); lo.y = bf16_rte(v.y - bf16_f(hi.y));
                hi.z = bf16_rte(v.z); lo.z = bf16_rte(v.z - bf16_f(hi.z));
                hi.w = bf16_rte(v.w); lo.w = bf16_rte(v.w - bf16_f(hi.w));
                *(ushort4*)&aHi[base] = hi;
                *(ushort4*)&aLo[base] = lo;
            }
        }
        {
#pragma unroll
            for (int rep = 0; rep < FOUT / 32; ++rep) {
                int idx = t + rep * 256;
                int fk = idx / (FOUT / 4);
                int fc = (idx % (FOUT / 4)) * 4;
                float4 v = *(const float4*)(W + (size_t)(k0 + fk) * FOUT + fc);
                const float* vp = &v.x;
#pragma unroll
                for (int s = 0; s < 4; ++s) {
                    unsigned short hi = bf16_rte(vp[s]);
                    wHi[(fc + s) * SR + fk] = hi;
                    wLo[(fc + s) * SR + fk] = bf16_rte(vp[s] - bf16_f(hi));
                }
            }
        }
        __syncthreads();

        bf16x8 ah[4], al[4], wh[CT], wl2[CT];
#pragma unroll
        for (int tt = 0; tt < 4; ++tt) {
            int off = (wn + tt * 16 + nl) * SR + q * 8;
            ah[tt] = *(const bf16x8*)&aHi[off];
            al[tt] = *(const bf16x8*)&aLo[off];
        }
#pragma unroll
        for (int uu = 0; uu < CT; ++uu) {
            int off = (wc + uu * 16 + nl) * SR + q * 8;
            wh[uu] = *(const bf16x8*)&wHi[off];
            wl2[uu] = *(const bf16x8*)&wLo[off];
        }
#pragma unroll
        for (int tt = 0; tt < 4; ++tt)
#pragma unroll
            for (int uu = 0; uu < CT; ++uu) {
                f32x4 a = acc[tt][uu];
                a = mfma16(al[tt], wh[uu], a);
                a = mfma16(ah[tt], wl2[uu], a);
                a = mfma16(ah[tt], wh[uu], a);
                acc[tt][uu] = a;
            }
        __syncthreads();
    }

#pragma unroll
    for (int uu = 0; uu < CT; ++uu) {
        int col = wc + uu * 16 + nl;
        if (ysel) {
            float bv = bias[col];
#pragma unroll
            for (int tt = 0; tt < 4; ++tt)
#pragma unroll
                for (int r = 0; r < 4; ++r) {
                    int node = node0 + wn + tt * 16 + q * 4 + r;
                    if (node < n) dstF[(size_t)node * FOUT + col] = acc[tt][uu][r] + bv;
                }
        } else {
#pragma unroll
            for (int tt = 0; tt < 4; ++tt)
#pragma unroll
                for (int r = 0; r < 4; ++r) {
                    int node = node0 + wn + tt * 16 + q * 4 + r;
                    if (node < n) dstH[(size_t)node * FOUT + col] = __float2half(acc[tt][uu][r]);
                }
        }
    }
}

__global__ __launch_bounds__(256, 2) void gemm1(
    const float* __restrict__ X, const float* __restrict__ WA,
    const float* __restrict__ WB, const float* __restrict__ bias,
    __half* __restrict__ dstH, float* __restrict__ dstF, int n) {
    gemm_body<128>(X, WA, WB, bias, dstH, dstF, n);
}

__global__ __launch_bounds__(256, 2) void gemm2(
    const float* __restrict__ X, const float* __restrict__ WA,
    const float* __restrict__ WB, const float* __restrict__ bias,
    __half* __restrict__ dstH, float* __restrict__ dstF, int n) {
    gemm_body<64>(X, WA, WB, bias, dstH, dstF, n);
}

// ---------------- fused aggregations (2 nodes/wave, wide loads) --------------

// h = relu(mean-gather(u fp16) + v). 2 nodes/wave: 32 lanes x 8 B per edge.
__global__ void agg1(const __half* __restrict__ u, const float* __restrict__ v,
                     const int* __restrict__ csr, const int* __restrict__ start,
                     const int* __restrict__ deg, float* __restrict__ h, int n) {
    int gid = blockIdx.x * blockDim.x + threadIdx.x;
    int wave = gid >> 6, lane = gid & 63;
    int half = lane >> 5, fl = lane & 31;
    int node = wave * 2 + half;
    if (node >= n) return;
    int s = start[node], d = deg[node];
    const float2* u2 = (const float2*)u;  // 4 halfs per float2
    float4 acc = {0.f, 0.f, 0.f, 0.f};
    int j = 0;
    for (; j + 2 <= d; j += 2) {
        int i0 = csr[s + j], i1 = csr[s + j + 1];
        float2 r0 = u2[(size_t)i0 * 32 + fl];
        float2 r1 = u2[(size_t)i1 * 32 + fl];
        float2 a0 = __half22float2(*(const __half2*)&r0.x);
        float2 b0 = __half22float2(*(const __half2*)&r0.y);
        float2 a1 = __half22float2(*(const __half2*)&r1.x);
        float2 b1 = __half22float2(*(const __half2*)&r1.y);
        acc.x += a0.x + a1.x;
        acc.y += a0.y + a1.y;
        acc.z += b0.x + b1.x;
        acc.w += b0.y + b1.y;
    }
    if (j < d) {
        float2 r0 = u2[(size_t)csr[s + j] * 32 + fl];
        float2 a0 = __half22float2(*(const __half2*)&r0.x);
        float2 b0 = __half22float2(*(const __half2*)&r0.y);
        acc.x += a0.x; acc.y += a0.y; acc.z += b0.x; acc.w += b0.y;
    }
    float inv = 1.0f / (float)max(d, 1);
    float4 vv = ((const float4*)v)[(size_t)node * 32 + fl];
    float4 r;
    r.x = fmaxf(acc.x * inv + vv.x, 0.f);
    r.y = fmaxf(acc.y * inv + vv.y, 0.f);
    r.z = fmaxf(acc.z * inv + vv.z, 0.f);
    r.w = fmaxf(acc.w * inv + vv.w, 0.f);
    ((float4*)h)[(size_t)node * 32 + fl] = r;
}

// out += mean-gather(p fp16). 2 nodes/wave: 32 lanes x 4 B per edge.
__global__ void agg2(const __half* __restrict__ p, const int* __restrict__ csr,
                     const int* __restrict__ start, const int* __restrict__ deg,
                     float* __restrict__ out, int n) {
    int gid = blockIdx.x * blockDim.x + threadIdx.x;
    int wave = gid >> 6, lane = gid & 63;
    int half = lane >> 5, fl = lane & 31;
    int node = wave * 2 + half;
    if (node >= n) return;
    int s = start[node], d = deg[node];
    const __half2* p2 = (const __half2*)p;
    float ax = 0.f, ay = 0.f, bx = 0.f, by = 0.f;
    int j = 0;
    for (; j + 2 <= d; j += 2) {
        int i0 = csr[s + j], i1 = csr[s + j + 1];
        float2 v0 = __half22float2(p2[(size_t)i0 * 32 + fl]);
        float2 v1 = __half22float2(p2[(size_t)i1 * 32 + fl]);
        ax += v0.x; ay += v0.y;
        bx += v1.x; by += v1.y;
    }
    if (j < d) {
        float2 v0 = __half22float2(p2[(size_t)csr[s + j] * 32 + fl]);
        ax += v0.x; ay += v0.y;
    }
    float inv = 1.0f / (float)max(d, 1);
    size_t o = (size_t)node * 32 + fl;
    float2 cu = ((float2*)out)[o];
    cu.x += (ax + bx) * inv;
    cu.y += (ay + by) * inv;
    ((float2*)out)[o] = cu;
}

// ---------------- launch ----------------

extern "C" void kernel_launch(void* const* d_in, const int* in_sizes, int n_in,
                              void* d_out, int out_size, void* d_ws, size_t ws_size,
                              hipStream_t stream) {
    const float* x   = (const float*)d_in[0];
    const int*   ei  = (const int*)d_in[1];
    const float* Wl1 = (const float*)d_in[2];
    const float* Wr1 = (const float*)d_in[3];
    const float* b1  = (const float*)d_in[4];
    const float* Wl2 = (const float*)d_in[5];
    const float* Wr2 = (const float*)d_in[6];
    const float* b2  = (const float*)d_in[7];
    float* out = (float*)d_out;

    int Nn = in_sizes[0] / 128;
    int E  = in_sizes[1] / 2;
    const int* src = ei;
    const int* dst = ei + E;
    int nb = (Nn + 127) / 128;  // 782 <= MAXNB

    char* ws = (char*)d_ws;
    auto alloc = [&](size_t bytes) -> char* {
        char* pp = ws;
        ws += (bytes + 255) / 256 * 256;
        return pp;
    };
    int* bcnt   = (int*)alloc((size_t)nb * 4);
    int* boff   = (int*)alloc((size_t)nb * 4);
    int* bcur   = (int*)alloc((size_t)nb * 4);
    int* start  = (int*)alloc((size_t)Nn * 4);
    int* deg    = (int*)alloc((size_t)Nn * 4);
    int* csr    = (int*)alloc((size_t)E * 4);
    __half* u   = (__half*)alloc((size_t)Nn * 128 * 2);
    float* v    = (float*)alloc((size_t)Nn * 128 * 4);
    float* h    = (float*)alloc((size_t)Nn * 128 * 4);
    __half* p   = (__half*)alloc((size_t)Nn * 64 * 2);
    // pairs (12.8 MB) aliases v (51.2 MB): consumed by k_build before gemm1 writes v
    int2* pairs = (int2*)v;

    hipMemsetAsync(bcnt, 0, (size_t)nb * 4, stream);

    int chunk = (E + 255) / 256;  // 256 blocks for count/scatter passes
    k_bcount<<<256, 256, 0, stream>>>(dst, bcnt, E, chunk, nb);
    k_bscan<<<1, 1024, 0, stream>>>(bcnt, boff, bcur, nb);
    k_bscatter<<<256, 256, 0, stream>>>(src, dst, bcur, pairs, E, chunk, nb);
    k_build<<<nb, 256, 0, stream>>>(pairs, boff, csr, start, deg, Nn, nb, E);

    dim3 gg((Nn + 127) / 128, 2);
    // layer 1 (linearity): u = x@Wl1 (fp16), v = x@Wr1 + b1; h = relu(agg(u) + v)
    gemm1<<<gg, 256, 0, stream>>>(x, Wl1, Wr1, b1, u, v, Nn);
    agg1<<<(Nn + 7) / 8, 256, 0, stream>>>(u, v, csr, start, deg, h, Nn);
    // layer 2 (linearity): p = h@Wl2 (fp16), out = h@Wr2 + b2; out += agg(p)
    gemm2<<<gg, 256, 0, stream>>>(h, Wl2, Wr2, b2, p, out, Nn);
    agg2<<<(Nn + 7) / 8, 256, 0, stream>>>(p, csr, start, deg, out, Nn);
}

// Round 8
// 388.816 us; speedup vs baseline: 2.8672x; 1.0797x over previous
//
#include <hip/hip_runtime.h>
#include <hip/hip_fp16.h>

typedef __attribute__((ext_vector_type(8))) short bf16x8;
typedef __attribute__((ext_vector_type(4))) float f32x4;

__device__ __forceinline__ f32x4 mfma16(bf16x8 a, bf16x8 b, f32x4 c) {
    return __builtin_amdgcn_mfma_f32_16x16x32_bf16(a, b, c, 0, 0, 0);
}

__device__ __forceinline__ unsigned short bf16_rte(float f) {
    unsigned int u = __float_as_uint(f);
    unsigned int r = (u + 0x7FFFu + ((u >> 16) & 1u)) >> 16;
    return (unsigned short)r;
}
__device__ __forceinline__ float bf16_f(unsigned short h) {
    return __uint_as_float(((unsigned int)h) << 16);
}

// ---------------- weight pre-conversion to fragment layout ----------------
// W (K x F fp32, row-major) -> hi/lo bf16 at [col*K + k]. Run once per call.
__global__ void k_wconv(const float* __restrict__ W, unsigned short* __restrict__ hi,
                        unsigned short* __restrict__ lo, int K, int F) {
    int e = blockIdx.x * 256 + threadIdx.x;
    if (e >= K * F) return;
    int col = e / K, k = e - col * K;
    float v = W[(size_t)k * F + col];
    unsigned short h = bf16_rte(v);
    hi[e] = h;
    lo[e] = bf16_rte(v - bf16_f(h));
}

// ---------------- bucketed CSR build, two-level (round-7, works) ------------

#define MAXNB 1024

__global__ __launch_bounds__(256) void k_bcount(
    const int* __restrict__ dst, int* __restrict__ bcnt, int E, int chunk, int nb) {
    __shared__ int h[MAXNB];
    int t = threadIdx.x;
    for (int i = t; i < nb; i += 256) h[i] = 0;
    __syncthreads();
    int base = blockIdx.x * chunk;
    int end = min(base + chunk, E);
    for (int i = base + t; i < end; i += 256) atomicAdd(&h[dst[i] >> 7], 1);
    __syncthreads();
    for (int i = t; i < nb; i += 256)
        if (h[i]) atomicAdd(&bcnt[i], h[i]);
}

__global__ void k_bscan(const int* __restrict__ bcnt, int* __restrict__ boff,
                        int* __restrict__ bcur, int nb) {
    __shared__ int sh[1024];
    int t = threadIdx.x;
    int v = (t < nb) ? bcnt[t] : 0;
    sh[t] = v;
    __syncthreads();
    for (int off = 1; off < 1024; off <<= 1) {
        int u = (t >= off) ? sh[t - off] : 0;
        __syncthreads();
        sh[t] += u;
        __syncthreads();
    }
    if (t < nb) {
        int ex = sh[t] - v;
        boff[t] = ex;
        bcur[t] = ex;
    }
}

__global__ __launch_bounds__(256) void k_bscatter(
    const int* __restrict__ src, const int* __restrict__ dst,
    int* __restrict__ bcur, int2* __restrict__ pairs, int E, int chunk, int nb) {
    __shared__ int h[MAXNB];
    __shared__ int curs[MAXNB];
    int t = threadIdx.x;
    for (int i = t; i < nb; i += 256) h[i] = 0;
    __syncthreads();
    int base = blockIdx.x * chunk;
    int end = min(base + chunk, E);
    for (int i = base + t; i < end; i += 256) atomicAdd(&h[dst[i] >> 7], 1);
    __syncthreads();
    for (int i = t; i < nb; i += 256)
        curs[i] = h[i] ? atomicAdd(&bcur[i], h[i]) : 0;
    __syncthreads();
    for (int i = base + t; i < end; i += 256) {
        int d = dst[i];
        int p = atomicAdd(&curs[d >> 7], 1);
        pairs[p] = make_int2(d, src[i]);
    }
}

__global__ __launch_bounds__(256) void k_build(
    const int2* __restrict__ pairs, const int* __restrict__ boff,
    int* __restrict__ csr, int* __restrict__ start, int* __restrict__ deg,
    int n, int nb, int E) {
    __shared__ int scnt[128];
    __shared__ int soff[128];
    __shared__ int cur[128];
    int b = blockIdx.x;
    int t = threadIdx.x;
    int base = boff[b];
    int end = (b + 1 < nb) ? boff[b + 1] : E;
    if (t < 128) scnt[t] = 0;
    __syncthreads();
    for (int i = base + t; i < end; i += 256) {
        int2 e = pairs[i];
        atomicAdd(&scnt[e.x & 127], 1);
    }
    __syncthreads();
    if (t < 128) soff[t] = scnt[t];
    __syncthreads();
    for (int off = 1; off < 128; off <<= 1) {
        int val = 0;
        if (t < 128 && t >= off) val = soff[t - off];
        __syncthreads();
        if (t < 128) soff[t] += val;
        __syncthreads();
    }
    if (t < 128) {
        int c = scnt[t];
        int ex = soff[t] - c;
        int node = b * 128 + t;
        if (node < n) {
            start[node] = base + ex;
            deg[node] = c;
        }
        cur[t] = base + ex;
    }
    __syncthreads();
    for (int i = base + t; i < end; i += 256) {
        int2 e = pairs[i];
        int p = atomicAdd(&cur[e.x & 127], 1);
        csr[p] = e.y;
    }
}

// ---------------- MFMA dual GEMM, W from global frag arrays ----------------
// ysel=0: dstH = X@WA (fp16);  ysel=1: dstF = X@WB + bias (fp32).
// A (bf16 hi/lo) staged in LDS (SR=40 ushorts, 16B-aligned rows). W frags read
// straight from pre-converted global [col*128 + k] (L1/L2-resident), double-
// buffered in regs. Round-7 lesson: transposed W LDS staging = 16-way write
// conflicts (2.6e7 cycles); W never touches LDS now.

#define SR 40

template <int FOUT>
__device__ __forceinline__ void gemm_body(
    const float* __restrict__ X,
    const unsigned short* __restrict__ WHa, const unsigned short* __restrict__ WLa,
    const unsigned short* __restrict__ WHb, const unsigned short* __restrict__ WLb,
    const float* __restrict__ bias, __half* __restrict__ dstH,
    float* __restrict__ dstF, int n) {
    constexpr int CT = FOUT / 32;  // 16-col tiles per wave
    __shared__ unsigned short aHi[128 * SR], aLo[128 * SR];

    int t = threadIdx.x;
    int wv = t >> 6, l = t & 63, q = l >> 4, nl = l & 15;
    int wn = (wv & 1) * 64, wc = (wv >> 1) * (FOUT / 2);
    int node0 = blockIdx.x * 128;
    int ysel = blockIdx.y;
    const unsigned short* WH = ysel ? WHb : WHa;
    const unsigned short* WL = ysel ? WLb : WLa;

    int sn = t >> 1, sh2 = t & 1;
    int gn = min(node0 + sn, n - 1);
    const float4* ap = (const float4*)(X + (size_t)gn * 128);

    f32x4 acc[4][CT];
#pragma unroll
    for (int a = 0; a < 4; ++a)
#pragma unroll
        for (int b = 0; b < CT; ++b) acc[a][b] = (f32x4){0.f, 0.f, 0.f, 0.f};

    // W frag double buffer; preload chunk 0
    bf16x8 wh[2][CT], wl[2][CT];
#pragma unroll
    for (int uu = 0; uu < CT; ++uu) {
        int base = (wc + uu * 16 + nl) * 128 + q * 8;
        wh[0][uu] = *(const bf16x8*)&WH[base];
        wl[0][uu] = *(const bf16x8*)&WL[base];
    }

    for (int c = 0; c < 4; ++c) {
        // stage A chunk c: 128 nodes x 32 k, hi/lo split
#pragma unroll
        for (int i = 0; i < 4; ++i) {
            float4 v = ap[c * 8 + sh2 * 4 + i];
            int base = sn * SR + sh2 * 16 + i * 4;
            ushort4 hi, lo;
            hi.x = bf16_rte(v.x); lo.x = bf16_rte(v.x - bf16_f(hi.x));
            hi.y = bf16_rte(v.y); lo.y = bf16_rte(v.y - bf16_f(hi.y));
            hi.z = bf16_rte(v.z); lo.z = bf16_rte(v.z - bf16_f(hi.z));
            hi.w = bf16_rte(v.w); lo.w = bf16_rte(v.w - bf16_f(hi.w));
            *(ushort4*)&aHi[base] = hi;
            *(ushort4*)&aLo[base] = lo;
        }
        __syncthreads();

        // prefetch W frags for next chunk
        if (c < 3) {
#pragma unroll
            for (int uu = 0; uu < CT; ++uu) {
                int base = (wc + uu * 16 + nl) * 128 + (c + 1) * 32 + q * 8;
                wh[(c + 1) & 1][uu] = *(const bf16x8*)&WH[base];
                wl[(c + 1) & 1][uu] = *(const bf16x8*)&WL[base];
            }
        }

        bf16x8 ah[4], al[4];
#pragma unroll
        for (int tt = 0; tt < 4; ++tt) {
            int off = (wn + tt * 16 + nl) * SR + q * 8;
            ah[tt] = *(const bf16x8*)&aHi[off];
            al[tt] = *(const bf16x8*)&aLo[off];
        }
        int cb = c & 1;
#pragma unroll
        for (int tt = 0; tt < 4; ++tt)
#pragma unroll
            for (int uu = 0; uu < CT; ++uu) {
                f32x4 a = acc[tt][uu];
                a = mfma16(al[tt], wh[cb][uu], a);
                a = mfma16(ah[tt], wl[cb][uu], a);
                a = mfma16(ah[tt], wh[cb][uu], a);
                acc[tt][uu] = a;
            }
        __syncthreads();
    }

#pragma unroll
    for (int uu = 0; uu < CT; ++uu) {
        int col = wc + uu * 16 + nl;
        if (ysel) {
            float bv = bias[col];
#pragma unroll
            for (int tt = 0; tt < 4; ++tt)
#pragma unroll
                for (int r = 0; r < 4; ++r) {
                    int node = node0 + wn + tt * 16 + q * 4 + r;
                    if (node < n) dstF[(size_t)node * FOUT + col] = acc[tt][uu][r] + bv;
                }
        } else {
#pragma unroll
            for (int tt = 0; tt < 4; ++tt)
#pragma unroll
                for (int r = 0; r < 4; ++r) {
                    int node = node0 + wn + tt * 16 + q * 4 + r;
                    if (node < n) dstH[(size_t)node * FOUT + col] = __float2half(acc[tt][uu][r]);
                }
        }
    }
}

__global__ __launch_bounds__(256, 2) void gemm1(
    const float* __restrict__ X,
    const unsigned short* WHa, const unsigned short* WLa,
    const unsigned short* WHb, const unsigned short* WLb,
    const float* __restrict__ bias, __half* dstH, float* dstF, int n) {
    gemm_body<128>(X, WHa, WLa, WHb, WLb, bias, dstH, dstF, n);
}

__global__ __launch_bounds__(256, 2) void gemm2(
    const float* __restrict__ X,
    const unsigned short* WHa, const unsigned short* WLa,
    const unsigned short* WHb, const unsigned short* WLb,
    const float* __restrict__ bias, __half* dstH, float* dstF, int n) {
    gemm_body<64>(X, WHa, WLa, WHb, WLb, bias, dstH, dstF, n);
}

// ---------------- fused aggregations (2 nodes/wave, unroll-4) ---------------

__global__ void agg1(const __half* __restrict__ u, const float* __restrict__ v,
                     const int* __restrict__ csr, const int* __restrict__ start,
                     const int* __restrict__ deg, float* __restrict__ h, int n) {
    int gid = blockIdx.x * blockDim.x + threadIdx.x;
    int wave = gid >> 6, lane = gid & 63;
    int half = lane >> 5, fl = lane & 31;
    int node = wave * 2 + half;
    if (node >= n) return;
    int s = start[node], d = deg[node];
    const float2* u2 = (const float2*)u;  // 4 halfs per float2
    float4 A = {0.f, 0.f, 0.f, 0.f}, B = {0.f, 0.f, 0.f, 0.f};
    int j = 0;
    for (; j + 4 <= d; j += 4) {
        int i0 = csr[s + j], i1 = csr[s + j + 1], i2 = csr[s + j + 2], i3 = csr[s + j + 3];
        float2 r0 = u2[(size_t)i0 * 32 + fl];
        float2 r1 = u2[(size_t)i1 * 32 + fl];
        float2 r2 = u2[(size_t)i2 * 32 + fl];
        float2 r3 = u2[(size_t)i3 * 32 + fl];
        float2 a0 = __half22float2(*(const __half2*)&r0.x), b0 = __half22float2(*(const __half2*)&r0.y);
        float2 a1 = __half22float2(*(const __half2*)&r1.x), b1 = __half22float2(*(const __half2*)&r1.y);
        float2 a2 = __half22float2(*(const __half2*)&r2.x), b2 = __half22float2(*(const __half2*)&r2.y);
        float2 a3 = __half22float2(*(const __half2*)&r3.x), b3 = __half22float2(*(const __half2*)&r3.y);
        A.x += a0.x + a1.x; A.y += a0.y + a1.y;
        A.z += b0.x + b1.x; A.w += b0.y + b1.y;
        B.x += a2.x + a3.x; B.y += a2.y + a3.y;
        B.z += b2.x + b3.x; B.w += b2.y + b3.y;
    }
    for (; j < d; ++j) {
        float2 r0 = u2[(size_t)csr[s + j] * 32 + fl];
        float2 a0 = __half22float2(*(const __half2*)&r0.x), b0 = __half22float2(*(const __half2*)&r0.y);
        A.x += a0.x; A.y += a0.y; A.z += b0.x; A.w += b0.y;
    }
    float inv = 1.0f / (float)max(d, 1);
    float4 vv = ((const float4*)v)[(size_t)node * 32 + fl];
    float4 r;
    r.x = fmaxf((A.x + B.x) * inv + vv.x, 0.f);
    r.y = fmaxf((A.y + B.y) * inv + vv.y, 0.f);
    r.z = fmaxf((A.z + B.z) * inv + vv.z, 0.f);
    r.w = fmaxf((A.w + B.w) * inv + vv.w, 0.f);
    ((float4*)h)[(size_t)node * 32 + fl] = r;
}

__global__ void agg2(const __half* __restrict__ p, const int* __restrict__ csr,
                     const int* __restrict__ start, const int* __restrict__ deg,
                     float* __restrict__ out, int n) {
    int gid = blockIdx.x * blockDim.x + threadIdx.x;
    int wave = gid >> 6, lane = gid & 63;
    int half = lane >> 5, fl = lane & 31;
    int node = wave * 2 + half;
    if (node >= n) return;
    int s = start[node], d = deg[node];
    const __half2* p2 = (const __half2*)p;
    float ax = 0.f, ay = 0.f, bx = 0.f, by = 0.f, cx = 0.f, cy = 0.f, dx = 0.f, dy = 0.f;
    int j = 0;
    for (; j + 4 <= d; j += 4) {
        int i0 = csr[s + j], i1 = csr[s + j + 1], i2 = csr[s + j + 2], i3 = csr[s + j + 3];
        float2 v0 = __half22float2(p2[(size_t)i0 * 32 + fl]);
        float2 v1 = __half22float2(p2[(size_t)i1 * 32 + fl]);
        float2 v2 = __half22float2(p2[(size_t)i2 * 32 + fl]);
        float2 v3 = __half22float2(p2[(size_t)i3 * 32 + fl]);
        ax += v0.x; ay += v0.y;
        bx += v1.x; by += v1.y;
        cx += v2.x; cy += v2.y;
        dx += v3.x; dy += v3.y;
    }
    for (; j < d; ++j) {
        float2 v0 = __half22float2(p2[(size_t)csr[s + j] * 32 + fl]);
        ax += v0.x; ay += v0.y;
    }
    float inv = 1.0f / (float)max(d, 1);
    size_t o = (size_t)node * 32 + fl;
    float2 cu = ((float2*)out)[o];
    cu.x += ((ax + bx) + (cx + dx)) * inv;
    cu.y += ((ay + by) + (cy + dy)) * inv;
    ((float2*)out)[o] = cu;
}

// ---------------- launch ----------------

extern "C" void kernel_launch(void* const* d_in, const int* in_sizes, int n_in,
                              void* d_out, int out_size, void* d_ws, size_t ws_size,
                              hipStream_t stream) {
    const float* x   = (const float*)d_in[0];
    const int*   ei  = (const int*)d_in[1];
    const float* Wl1 = (const float*)d_in[2];
    const float* Wr1 = (const float*)d_in[3];
    const float* b1  = (const float*)d_in[4];
    const float* Wl2 = (const float*)d_in[5];
    const float* Wr2 = (const float*)d_in[6];
    const float* b2  = (const float*)d_in[7];
    float* out = (float*)d_out;

    int Nn = in_sizes[0] / 128;
    int E  = in_sizes[1] / 2;
    const int* src = ei;
    const int* dst = ei + E;
    int nb = (Nn + 127) / 128;  // 782 <= MAXNB

    char* ws = (char*)d_ws;
    auto alloc = [&](size_t bytes) -> char* {
        char* pp = ws;
        ws += (bytes + 255) / 256 * 256;
        return pp;
    };
    int* bcnt   = (int*)alloc((size_t)nb * 4);
    int* boff   = (int*)alloc((size_t)nb * 4);
    int* bcur   = (int*)alloc((size_t)nb * 4);
    int* start  = (int*)alloc((size_t)Nn * 4);
    int* deg    = (int*)alloc((size_t)Nn * 4);
    int* csr    = (int*)alloc((size_t)E * 4);
    __half* u   = (__half*)alloc((size_t)Nn * 128 * 2);
    float* v    = (float*)alloc((size_t)Nn * 128 * 4);
    float* h    = (float*)alloc((size_t)Nn * 128 * 4);
    __half* p   = (__half*)alloc((size_t)Nn * 64 * 2);
    unsigned short* w1ah = (unsigned short*)alloc(128 * 128 * 2);
    unsigned short* w1al = (unsigned short*)alloc(128 * 128 * 2);
    unsigned short* w1bh = (unsigned short*)alloc(128 * 128 * 2);
    unsigned short* w1bl = (unsigned short*)alloc(128 * 128 * 2);
    unsigned short* w2ah = (unsigned short*)alloc(64 * 128 * 2);
    unsigned short* w2al = (unsigned short*)alloc(64 * 128 * 2);
    unsigned short* w2bh = (unsigned short*)alloc(64 * 128 * 2);
    unsigned short* w2bl = (unsigned short*)alloc(64 * 128 * 2);
    // pairs (12.8 MB) aliases v (51.2 MB): consumed by k_build before gemm1 writes v
    int2* pairs = (int2*)v;

    hipMemsetAsync(bcnt, 0, (size_t)nb * 4, stream);

    k_wconv<<<64, 256, 0, stream>>>(Wl1, w1ah, w1al, 128, 128);
    k_wconv<<<64, 256, 0, stream>>>(Wr1, w1bh, w1bl, 128, 128);
    k_wconv<<<32, 256, 0, stream>>>(Wl2, w2ah, w2al, 128, 64);
    k_wconv<<<32, 256, 0, stream>>>(Wr2, w2bh, w2bl, 128, 64);

    int chunk = (E + 255) / 256;
    k_bcount<<<256, 256, 0, stream>>>(dst, bcnt, E, chunk, nb);
    k_bscan<<<1, 1024, 0, stream>>>(bcnt, boff, bcur, nb);
    k_bscatter<<<256, 256, 0, stream>>>(src, dst, bcur, pairs, E, chunk, nb);
    k_build<<<nb, 256, 0, stream>>>(pairs, boff, csr, start, deg, Nn, nb, E);

    dim3 gg((Nn + 127) / 128, 2);
    // layer 1 (linearity): u = x@Wl1 (fp16), v = x@Wr1 + b1; h = relu(agg(u) + v)
    gemm1<<<gg, 256, 0, stream>>>(x, w1ah, w1al, w1bh, w1bl, b1, u, v, Nn);
    agg1<<<(Nn + 7) / 8, 256, 0, stream>>>(u, v, csr, start, deg, h, Nn);
    // layer 2 (linearity): p = h@Wl2 (fp16), out = h@Wr2 + b2; out += agg(p)
    gemm2<<<gg, 256, 0, stream>>>(h, w2ah, w2al, w2bh, w2bl, b2, p, out, Nn);
    agg2<<<(Nn + 7) / 8, 256, 0, stream>>>(p, csr, start, deg, out, Nn);
}